// Round 17
// baseline (434.253 us; speedup 1.0000x reference)
//
#include <hip/hip_runtime.h>
#include <cstdint>
#include <cstddef>

#define BB 256
#define TT 512
#define KK 128
#define START_TAG 126
#define STOP_TAG 127
#define NEGV (-10000.0f)
#define NINF (-__builtin_huge_valf())

// ---- DPP helpers -----------------------------------------------------------
template<int CTRL>
__device__ __forceinline__ float dppf(float v, float old) {
  return __int_as_float(__builtin_amdgcn_update_dpp(
      __float_as_int(old), __float_as_int(v), CTRL, 0xf, 0xf, false));
}
template<int CTRL>
__device__ __forceinline__ int dppi(int v, int old) {
  return __builtin_amdgcn_update_dpp(old, v, CTRL, 0xf, 0xf, false);
}
__device__ __forceinline__ float wave_max63(float x) {
  x = fmaxf(x, dppf<0x111>(x, NINF));
  x = fmaxf(x, dppf<0x112>(x, NINF));
  x = fmaxf(x, dppf<0x114>(x, NINF));
  x = fmaxf(x, dppf<0x118>(x, NINF));
  x = fmaxf(x, dppf<0x142>(x, NINF));
  x = fmaxf(x, dppf<0x143>(x, NINF));
  return x;
}
__device__ __forceinline__ float max3f(float a, float b, float c) {
  float d;
  asm("v_max3_f32 %0, %1, %2, %3" : "=v"(d) : "v"(a), "v"(b), "v"(c));
  return d;
}
__device__ __forceinline__ int paddr(int i) { return (i >> 5) * 36 + (i & 31); }

// ---------------------------------------------------------------------------
// crf512g2: grid 256 blocks x 512 threads (8 waves, 1 block/CU, 2 waves/SIMD)
//   blocks [0,128)   : Viterbi values for chains b=2*bid, 2*bid+1.
//   blocks [128,256) : forward-alg (log-free, rescale/4) + gold for 2 chains.
// G=2 AMORTIZATION: the compiler insists on re-streaming the 32-float trans
// slice every step (~100 inst of reload machinery/thread/step, proven
// unremovable in R8-R16). Each streamed value now feeds BOTH chains' compute,
// halving the bloat per chain. Thread = (to = tid>>2, h = tid&3).
// LDS: BUF[2][2][144], h*36-section layout -> per-instruction broadcast
// addresses at banks (36h+4c)%32 = 4 distinct -> conflict-free.
// ---------------------------------------------------------------------------
__global__ __launch_bounds__(512, 2) void crf512g2(
    const float* __restrict__ feats, const float* __restrict__ trans,
    const int* __restrict__ tags,
    float* __restrict__ pscore, int* __restrict__ lasttag,
    float* __restrict__ alphaS, float* __restrict__ gb)
{
  const int bid = blockIdx.x;
  const bool isv = bid < (BB / 2);
  const int b0 = (isv ? bid : bid - BB / 2) * 2;
  const int tid = threadIdx.x;
  const int to = tid >> 2;             // 0..127
  const int h  = tid & 3;              // 32-from slice
  const int lane = tid & 63;
  const int wv = tid >> 6;             // 0..7

  __shared__ __align__(16) float BUF[2][2][144]; // dbuf x chain x padded row
  __shared__ __align__(16) float pwm0[8], pwm1[8];
  __shared__ float vitm[2][2]; __shared__ int viti[2][2];
  __shared__ float reds[2][2]; __shared__ float redg[2][8];

  // 32-from transition slice: raw (vit) / exp (fwd). Compiler will stream
  // it from L1 every step regardless (R8-R16); value-in-flight serves both
  // chains.
  float R[32];
  {
    const float4* tr = (const float4*)(trans + (size_t)to * KK + h * 32);
#pragma unroll
    for (int c = 0; c < 8; ++c) {
      float4 v = tr[c];
      if (isv) { R[4*c+0]=v.x; R[4*c+1]=v.y; R[4*c+2]=v.z; R[4*c+3]=v.w; }
      else     { R[4*c+0]=__expf(v.x); R[4*c+1]=__expf(v.y);
                 R[4*c+2]=__expf(v.z); R[4*c+3]=__expf(v.w); }
    }
  }

  if (h == 0) {
    float init_v = (to == START_TAG) ? 0.0f : NEGV;
    float init_f = (to == START_TAG) ? 1.0f : 0.0f;
    BUF[0][0][paddr(to)] = isv ? init_v : init_f;
    BUF[0][1][paddr(to)] = isv ? init_v : init_f;
  }
  __syncthreads();

  const float* fbs0 = feats + (size_t)(b0 + 0) * TT * KK + to;
  const float* fbs1 = feats + (size_t)(b0 + 1) * TT * KK + to;
  float* aS0 = alphaS + (size_t)(b0 + 0) * TT * KK + to;
  float* aS1 = alphaS + (size_t)(b0 + 1) * TT * KK + to;

  float M0 = 0.0f, M1 = 0.0f;          // fwd per-chain log-scales
  float f0 = fbs0[0], f1 = fbs1[0];
  int cur = 0;

  for (int t = 0; t < TT; ++t) {
    const int tn = (t + 1 < TT) ? t + 1 : t;
    float f0n = fbs0[(size_t)tn * KK];
    float f1n = fbs1[(size_t)tn * KK];
    const float4* B0 = (const float4*)&BUF[cur][0][h * 36];
    const float4* B1 = (const float4*)&BUF[cur][1][h * 36];

    if (isv) {
      float4 p = B0[0], q = B1[0];
      float a0 = fmaxf(p.x + R[0], p.y + R[1]);
      float a1 = fmaxf(p.z + R[2], p.w + R[3]);
      float b0m = fmaxf(q.x + R[0], q.y + R[1]);
      float b1m = fmaxf(q.z + R[2], q.w + R[3]);
#pragma unroll
      for (int c = 1; c < 8; ++c) {
        p = B0[c]; q = B1[c];
        a0 = max3f(a0, p.x + R[4*c+0], p.y + R[4*c+1]);
        a1 = max3f(a1, p.z + R[4*c+2], p.w + R[4*c+3]);
        b0m = max3f(b0m, q.x + R[4*c+0], q.y + R[4*c+1]);
        b1m = max3f(b1m, q.z + R[4*c+2], q.w + R[4*c+3]);
      }
      float ma = fmaxf(a0, a1);
      float mb = fmaxf(b0m, b1m);
      ma = fmaxf(ma, dppf<0xB1>(ma, ma));
      ma = fmaxf(ma, dppf<0x4E>(ma, ma));
      mb = fmaxf(mb, dppf<0xB1>(mb, mb));
      mb = fmaxf(mb, dppf<0x4E>(mb, mb));
      if (h == 0) {
        float av0 = ma + f0, av1 = mb + f1;
        BUF[cur ^ 1][0][paddr(to)] = av0;
        BUF[cur ^ 1][1][paddr(to)] = av1;
        aS0[(size_t)t * KK] = av0;
        aS1[(size_t)t * KK] = av1;
      }
    } else {
      float c0 = 1.0f, c1 = 1.0f;
      if ((t & 3) == 0 && t) {              // consume previous phase-3 maxes
        float4 w0 = *(const float4*)&pwm0[0];
        float4 w1 = *(const float4*)&pwm0[4];
        float pm0 = fmaxf(fmaxf(fmaxf(w0.x, w0.y), fmaxf(w0.z, w0.w)),
                          fmaxf(fmaxf(w1.x, w1.y), fmaxf(w1.z, w1.w)));
        float4 x0 = *(const float4*)&pwm1[0];
        float4 x1 = *(const float4*)&pwm1[4];
        float pm1 = fmaxf(fmaxf(fmaxf(x0.x, x0.y), fmaxf(x0.z, x0.w)),
                          fmaxf(fmaxf(x1.x, x1.y), fmaxf(x1.z, x1.w)));
        M0 += __logf(pm0); c0 = 1.0f / pm0;
        M1 += __logf(pm1); c1 = 1.0f / pm1;
      }
      float4 p = B0[0], q = B1[0];
      float sa0 = R[0]*p.x, sa1 = R[1]*p.y, sa2 = R[2]*p.z, sa3 = R[3]*p.w;
      float sb0 = R[0]*q.x, sb1 = R[1]*q.y, sb2 = R[2]*q.z, sb3 = R[3]*q.w;
#pragma unroll
      for (int c = 1; c < 8; ++c) {
        p = B0[c]; q = B1[c];
        sa0 = fmaf(R[4*c+0], p.x, sa0); sa1 = fmaf(R[4*c+1], p.y, sa1);
        sa2 = fmaf(R[4*c+2], p.z, sa2); sa3 = fmaf(R[4*c+3], p.w, sa3);
        sb0 = fmaf(R[4*c+0], q.x, sb0); sb1 = fmaf(R[4*c+1], q.y, sb1);
        sb2 = fmaf(R[4*c+2], q.z, sb2); sb3 = fmaf(R[4*c+3], q.w, sb3);
      }
      float s = (sa0 + sa1) + (sa2 + sa3);
      float u = (sb0 + sb1) + (sb2 + sb3);
      s = s + dppf<0xB1>(s, s); s = s + dppf<0x4E>(s, s);
      u = u + dppf<0xB1>(u, u); u = u + dppf<0x4E>(u, u);
      float e0 = __expf(f0), e1 = __expf(f1);
      if ((t & 3) == 0 && t) { e0 *= c0; e1 *= c1; }
      float pv0 = s * e0, pv1 = u * e1;
      if (h == 0) {
        BUF[cur ^ 1][0][paddr(to)] = pv0;
        BUF[cur ^ 1][1][paddr(to)] = pv1;
      }
      if ((t & 3) == 3) {                   // publish wave maxes of P
        float wm0 = wave_max63(pv0);
        float wm1 = wave_max63(pv1);
        if (lane == 63) { pwm0[wv] = wm0; pwm1[wv] = wm1; }
      }
    }
    __syncthreads();
    cur ^= 1;
    f0 = f0n; f1 = f1n;
  }

  // ---- terminal ----
  if (isv) {
    if (tid < KK) {
      float ts = trans[(size_t)STOP_TAG * KK + tid];
#pragma unroll
      for (int g = 0; g < 2; ++g) {
        float term = BUF[cur][g][paddr(tid)] + ts;
        float m = term; int i = tid;
#pragma unroll
        for (int off = 1; off < 64; off <<= 1) {
          float mo = __shfl_xor(m, off, 64);
          int   io = __shfl_xor(i, off, 64);
          if (mo > m || (mo == m && io < i)) { m = mo; i = io; }
        }
        if (lane == 0) { vitm[g][tid >> 6] = m; viti[g][tid >> 6] = i; }
      }
    }
    __syncthreads();
    if (tid < 2) {
      int g = tid;
      float m = vitm[g][0]; int i = viti[g][0];
      if (vitm[g][1] > m || (vitm[g][1] == m && viti[g][1] < i)) {
        m = vitm[g][1]; i = viti[g][1];
      }
      pscore[b0 + g] = m; lasttag[b0 + g] = i;
    }
  } else {
    if (tid < KK) {
      float es = __expf(trans[(size_t)STOP_TAG * KK + tid]);
#pragma unroll
      for (int g = 0; g < 2; ++g) {
        float e = BUF[cur][g][paddr(tid)] * es;
#pragma unroll
        for (int off = 1; off < 64; off <<= 1) e += __shfl_xor(e, off, 64);
        if (lane == 0) reds[g][tid >> 6] = e;
      }
    }
    // fused gold score: t = tid (512 = TT), both chains
#pragma unroll
    for (int g = 0; g < 2; ++g) {
      const int* tg = tags + (size_t)(b0 + g) * TT;
      const float* fg = feats + (size_t)(b0 + g) * TT * KK;
      int ct = tg[tid];
      int pv2 = (tid == 0) ? START_TAG : tg[tid - 1];
      float gl = trans[(size_t)ct * KK + pv2] + fg[(size_t)tid * KK + ct];
      if (tid == TT - 1) gl += trans[(size_t)STOP_TAG * KK + ct];
#pragma unroll
      for (int off = 1; off < 64; off <<= 1) gl += __shfl_xor(gl, off, 64);
      if (lane == 0) redg[g][wv] = gl;
    }
    __syncthreads();
    if (tid < 2) {
      int g = tid;
      float sg = 0.f;
#pragma unroll
      for (int w = 0; w < 8; ++w) sg += redg[g][w];
      // M0/M1 are wave-uniform; tid 0,1 are in wave 0 and hold both.
      float Mg = g ? M1 : M0;
      gb[b0 + g] = (Mg + __logf(reds[g][0] + reds[g][1])) - sg;
    }
  }
}

// ---------------------------------------------------------------------------
// backtrace_loss: blocks [0,BB) backtrace per b (256 threads stage trans;
// wave 0 walks); block BB reduces loss.
// ---------------------------------------------------------------------------
__global__ __launch_bounds__(256) void backtrace_loss(
    const float* __restrict__ alphaS, const float* __restrict__ trans,
    const int* __restrict__ lasttag, const float* __restrict__ gb,
    float* __restrict__ pred, float* __restrict__ loss_out)
{
  const int tid = threadIdx.x;
  const int lane = tid & 63;
  if (blockIdx.x == BB) {
    if (tid < 64) {
      float v = gb[lane] + gb[lane + 64] + gb[lane + 128] + gb[lane + 192];
#pragma unroll
      for (int off = 1; off < 64; off <<= 1) v += __shfl_xor(v, off, 64);
      if (lane == 0) loss_out[0] = v / (float)(BB * TT);
    }
    return;
  }
  const int b = blockIdx.x;
  __shared__ float tl[KK * KK];                 // 64 KB
  {
    const float4* src = (const float4*)trans;
    float4* dst = (float4*)tl;
#pragma unroll
    for (int i = 0; i < (KK * KK / 4) / 256; ++i) dst[tid + i * 256] = src[tid + i * 256];
  }
  const float* arow = alphaS + (size_t)b * TT * KK;
  float p0[8], p1[8];
  if (tid < 64) {
#pragma unroll
    for (int j = 0; j < 8; ++j) {
      int r = TT - 2 - j;
      p0[j] = arow[(size_t)r * KK + lane];
      p1[j] = arow[(size_t)r * KK + 64 + lane];
    }
  }
  __syncthreads();
  if (tid >= 64) return;

  int tag = lasttag[b];
  if (lane == 0) pred[(size_t)b * TT + (TT - 1)] = (float)tag;

  for (int rb = TT - 2; rb >= 0; rb -= 8) {
#pragma unroll
    for (int j = 0; j < 8; ++j) {
      int r = rb - j;
      if (r >= 0) {
        float x0 = p0[j] + tl[tag * KK + lane];
        float x1 = p1[j] + tl[tag * KK + 64 + lane];
        float m = fmaxf(x0, x1);
        float M = wave_max63(m);
        M = __int_as_float(__builtin_amdgcn_readlane(__float_as_int(M), 63));
        unsigned long long b0 = __ballot(x0 == M);
        unsigned long long b1 = __ballot(x1 == M);
        tag = b0 ? (int)__builtin_ctzll(b0) : 64 + (int)__builtin_ctzll(b1);
        if (lane == 0) pred[(size_t)b * TT + r] = (float)tag;
        int rp = r - 8;
        if (rp >= 0) {
          p0[j] = arow[(size_t)rp * KK + lane];
          p1[j] = arow[(size_t)rp * KK + 64 + lane];
        }
      }
    }
  }
}

// ===========================================================================
// Fallback path (ws too small for 64MB alpha store): R2-proven kernels.
// ===========================================================================
__global__ __launch_bounds__(768) void crf_main_fb(
    const float* __restrict__ feats, const float* __restrict__ trans,
    float* __restrict__ logz, float* __restrict__ pscore,
    int* __restrict__ lasttag, uint8_t* __restrict__ bptr)
{
  const int b = blockIdx.x;
  const int tid = threadIdx.x;
  const bool is_fwd = tid < 256;
  const int lane = tid & 63;

  __shared__ __align__(16) float P[2][144];
  __shared__ __align__(16) float AV[2][144];
  __shared__ __align__(16) float redmF[2][4];
  __shared__ float reds[4];
  __shared__ float vitm[8];
  __shared__ int   viti[8];

  int myto, h;
  if (is_fwd) { myto = tid >> 1; h = tid & 1; }
  else { int q = tid - 256; myto = q >> 2; h = q & 3; }

  float R[64];
  if (is_fwd) {
    const float4* tr = (const float4*)(trans + (size_t)myto * KK + h * 64);
#pragma unroll
    for (int c = 0; c < 16; ++c) {
      float4 v = tr[c];
      R[4*c+0]=expf(v.x); R[4*c+1]=expf(v.y); R[4*c+2]=expf(v.z); R[4*c+3]=expf(v.w);
    }
  } else {
    const float4* tr = (const float4*)(trans + (size_t)myto * KK + h * 32);
#pragma unroll
    for (int c = 0; c < 8; ++c) {
      float4 v = tr[c];
      R[4*c+0]=v.x; R[4*c+1]=v.y; R[4*c+2]=v.z; R[4*c+3]=v.w;
    }
  }

  if (is_fwd) { if (h == 0) P[0][paddr(myto)] = (myto==START_TAG)?1.0f:0.0f; }
  else        { if (h == 0) AV[0][paddr(myto)] = (myto==START_TAG)?0.0f:NEGV; }
  if (tid < 4) redmF[1][tid] = 0.0f;
  __syncthreads();

  const float* fb = feats + (size_t)b * TT * KK + myto;
  uint8_t* bp = bptr + (size_t)b * TT * KK + myto;

  float fcur = fb[0];
  float Mprev = 0.0f;
  float aCarry = 0.0f;
  int cur = 0;

  for (int t = 0; t < TT; ++t) {
    const int tn = (t + 1 < TT) ? t + 1 : t;
    float fnext = fb[(size_t)tn * KK];
    const int rd = (t + 1) & 1, wr = t & 1;

    if (is_fwd) {
      float4 rv = *(const float4*)&redmF[rd][0];
      float M1 = fmaxf(fmaxf(rv.x, rv.y), fmaxf(rv.z, rv.w));
      const float* Pc = &P[cur][0];
      const int base = h * 72;
      float s0=0.f, s1=0.f, s2=0.f, s3=0.f;
#pragma unroll
      for (int c = 0; c < 16; ++c) {
        float4 p = *(const float4*)&Pc[base + (c>>3)*36 + (c&7)*4];
        s0 = fmaf(R[4*c+0], p.x, s0);
        s1 = fmaf(R[4*c+1], p.y, s1);
        s2 = fmaf(R[4*c+2], p.z, s2);
        s3 = fmaf(R[4*c+3], p.w, s3);
      }
      float s = (s0 + s1) + (s2 + s3);
      s = s + dppf<0xB1>(s, s);
      float a = Mprev + logf(s) + fcur;
      float wm = wave_max63(a);
      if (lane == 63) redmF[wr][tid >> 6] = wm;
      float pv = expf(a - M1);
      if (h == 0) P[cur ^ 1][paddr(myto)] = pv;
      Mprev = M1;
      aCarry = a;
    } else {
      const float* Ac = &AV[cur][0];
      const int base = h * 36;
      const int fb0 = h * 32;
      float4 p0 = *(const float4*)&Ac[base];
      float m0 = p0.x + R[0], m1 = p0.y + R[1], m2 = p0.z + R[2], m3 = p0.w + R[3];
      int i0 = fb0, i1 = fb0+1, i2 = fb0+2, i3 = fb0+3;
#pragma unroll
      for (int c = 1; c < 8; ++c) {
        float4 p = *(const float4*)&Ac[base + c*4];
        float v0 = p.x + R[4*c+0]; if (v0 > m0) { m0 = v0; i0 = fb0+4*c+0; }
        float v1 = p.y + R[4*c+1]; if (v1 > m1) { m1 = v1; i1 = fb0+4*c+1; }
        float v2 = p.z + R[4*c+2]; if (v2 > m2) { m2 = v2; i2 = fb0+4*c+2; }
        float v3 = p.w + R[4*c+3]; if (v3 > m3) { m3 = v3; i3 = fb0+4*c+3; }
      }
      float m = m0; int i = i0;
      if (m1 > m || (m1 == m && i1 < i)) { m = m1; i = i1; }
      if (m2 > m || (m2 == m && i2 < i)) { m = m2; i = i2; }
      if (m3 > m || (m3 == m && i3 < i)) { m = m3; i = i3; }
      { float mo = dppf<0xB1>(m, m); int io = dppi<0xB1>(i, i);
        if (mo > m || (mo == m && io < i)) { m = mo; i = io; } }
      { float mo = dppf<0x4E>(m, m); int io = dppi<0x4E>(i, i);
        if (mo > m || (mo == m && io < i)) { m = mo; i = io; } }
      float a = m + fcur;
      if (h == 0) { AV[cur ^ 1][paddr(myto)] = a; bp[(size_t)t * KK] = (uint8_t)i; }
      aCarry = a;
    }
    __syncthreads();
    cur ^= 1;
    fcur = fnext;
  }

  float tstop = trans[(size_t)STOP_TAG * KK + myto];
  float term = aCarry + tstop;
  float M = 0.0f;
  if (is_fwd) {
    float wm = wave_max63(term);
    if (lane == 63) redmF[0][tid >> 6] = wm;
  } else {
    float m = term; int i = myto;
#pragma unroll
    for (int off = 1; off < 64; off <<= 1) {
      float mo = __shfl_xor(m, off, 64);
      int   io = __shfl_xor(i, off, 64);
      if (mo > m || (mo == m && io < i)) { m = mo; i = io; }
    }
    if (lane == 0) { vitm[(tid>>6)-4] = m; viti[(tid>>6)-4] = i; }
  }
  __syncthreads();
  if (is_fwd) {
    float4 rv = *(const float4*)&redmF[0][0];
    M = fmaxf(fmaxf(rv.x, rv.y), fmaxf(rv.z, rv.w));
    float e = (h == 0) ? expf(term - M) : 0.0f;
#pragma unroll
    for (int off = 1; off < 64; off <<= 1) e += __shfl_xor(e, off, 64);
    if (lane == 0) reds[tid >> 6] = e;
  } else if (tid == 256) {
    float m = vitm[0]; int i = viti[0];
#pragma unroll
    for (int w = 1; w < 8; ++w)
      if (vitm[w] > m || (vitm[w] == m && viti[w] < i)) { m = vitm[w]; i = viti[w]; }
    pscore[b] = m; lasttag[b] = i;
  }
  __syncthreads();
  if (tid == 0) logz[b] = M + logf(reds[0] + reds[1] + reds[2] + reds[3]);
}

__global__ __launch_bounds__(256) void backtrace_kernel(
    const uint8_t* __restrict__ bptr, const int* __restrict__ lasttag,
    float* __restrict__ pred)
{
  const int b = blockIdx.x;
  const int tid = threadIdx.x;
  __shared__ __align__(16) uint8_t lb[(TT / 2) * KK];
  __shared__ int tagcarry;
  if (tid == 0) tagcarry = lasttag[b];

  for (int half = 1; half >= 0; --half) {
    __syncthreads();
    const float4* src = reinterpret_cast<const float4*>(
        bptr + ((size_t)b * TT + (size_t)half * (TT / 2)) * KK);
    float4* dst = reinterpret_cast<float4*>(lb);
    for (int i = tid; i < (TT / 2) * KK / 16; i += 256) dst[i] = src[i];
    __syncthreads();
    if (tid == 0) {
      int tag = tagcarry;
      for (int t = TT / 2 - 1; t >= 0; --t) {
        int gt = half * (TT / 2) + t;
        pred[(size_t)b * TT + gt] = (float)tag;
        tag = lb[t * KK + tag];
      }
      tagcarry = tag;
    }
  }
}

__global__ __launch_bounds__(64) void gold_kernel(
    const float* __restrict__ feats, const int* __restrict__ tags,
    const float* __restrict__ trans, const float* __restrict__ logz,
    float* __restrict__ gb)
{
  const int b = blockIdx.x;
  const int lane = threadIdx.x;
  const int* tg = tags + (size_t)b * TT;
  const float* fb = feats + (size_t)b * TT * KK;
  float g = 0.0f;
#pragma unroll
  for (int k = 0; k < TT / 64; ++k) {
    int t = lane * (TT / 64) + k;
    int ct = tg[t];
    int pv = (t == 0) ? START_TAG : tg[t - 1];
    g += trans[ct * KK + pv] + fb[(size_t)t * KK + ct];
  }
  if (lane == 63) g += trans[STOP_TAG * KK + tg[TT - 1]];
#pragma unroll
  for (int off = 1; off <= 32; off <<= 1) g += __shfl_xor(g, off, 64);
  if (lane == 0) gb[b] = logz[b] - g;
}

__global__ __launch_bounds__(256) void loss_reduce(
    const float* __restrict__ gb, float* __restrict__ out)
{
  const int tid = threadIdx.x;
  const int lane = tid & 63, wv = tid >> 6;
  float v = gb[tid];
#pragma unroll
  for (int off = 1; off <= 32; off <<= 1) v += __shfl_xor(v, off, 64);
  __shared__ float red[4];
  if (lane == 0) red[wv] = v;
  __syncthreads();
  if (tid == 0) out[0] = (red[0] + red[1] + red[2] + red[3]) / (float)(BB * TT);
}

// ---------------------------------------------------------------------------
extern "C" void kernel_launch(void* const* d_in, const int* in_sizes, int n_in,
                              void* d_out, int out_size, void* d_ws, size_t ws_size,
                              hipStream_t stream) {
  const float* feats = (const float*)d_in[0];
  const int*   tags  = (const int*)d_in[1];
  const float* trans = (const float*)d_in[2];

  float* out    = (float*)d_out;
  float* loss   = out;
  float* pscore = out + 1;
  float* pred   = out + 1 + BB;
  (void)in_sizes; (void)n_in; (void)out_size;

  const size_t alpha_bytes = (size_t)BB * TT * KK * sizeof(float);   // 64 MB
  const bool cheap = ws_size >= alpha_bytes + 4096;

  if (cheap) {
    float* alphaS  = (float*)d_ws;
    char*  wsend   = (char*)d_ws + alpha_bytes;
    int*   lasttag = (int*)(wsend);
    float* gb      = (float*)(wsend + BB * sizeof(int));
    crf512g2<<<BB, 512, 0, stream>>>(feats, trans, tags, pscore, lasttag,
                                     alphaS, gb);
    backtrace_loss<<<BB + 1, 256, 0, stream>>>(alphaS, trans, lasttag, gb,
                                               pred, loss);
  } else {
    uint8_t* bptr    = (uint8_t*)d_ws;
    char*    wsend   = (char*)d_ws + (size_t)BB * TT * KK;
    float*   logz    = (float*)(wsend);
    int*     lasttag = (int*)(wsend + BB * sizeof(float));
    float*   gb      = (float*)(wsend + BB * sizeof(float) + BB * sizeof(int));
    crf_main_fb<<<BB, 768, 0, stream>>>(feats, trans, logz, pscore, lasttag, bptr);
    backtrace_kernel<<<BB, 256, 0, stream>>>(bptr, lasttag, pred);
    gold_kernel<<<BB, 64, 0, stream>>>(feats, tags, trans, logz, gb);
    loss_reduce<<<1, 256, 0, stream>>>(gb, loss);
  }
}

// Round 18
// 348.859 us; speedup vs baseline: 1.2448x; 1.2448x over previous
//
#include <hip/hip_runtime.h>
#include <cstdint>
#include <cstddef>

#define BB 256
#define TT 512
#define KK 128
#define START_TAG 126
#define STOP_TAG 127
#define NEGV (-10000.0f)
#define NINF (-__builtin_huge_valf())

// ---- DPP helpers -----------------------------------------------------------
template<int CTRL>
__device__ __forceinline__ float dppf(float v, float old) {
  return __int_as_float(__builtin_amdgcn_update_dpp(
      __float_as_int(old), __float_as_int(v), CTRL, 0xf, 0xf, false));
}
template<int CTRL>
__device__ __forceinline__ int dppi(int v, int old) {
  return __builtin_amdgcn_update_dpp(old, v, CTRL, 0xf, 0xf, false);
}
__device__ __forceinline__ float wave_max63(float x) {
  x = fmaxf(x, dppf<0x111>(x, NINF));
  x = fmaxf(x, dppf<0x112>(x, NINF));
  x = fmaxf(x, dppf<0x114>(x, NINF));
  x = fmaxf(x, dppf<0x118>(x, NINF));
  x = fmaxf(x, dppf<0x142>(x, NINF));
  x = fmaxf(x, dppf<0x143>(x, NINF));
  return x;
}
__device__ __forceinline__ float max3f(float a, float b, float c) {
  float d;
  asm("v_max3_f32 %0, %1, %2, %3" : "=v"(d) : "v"(a), "v"(b), "v"(c));
  return d;
}
__device__ __forceinline__ int paddr(int i) { return (i >> 5) * 36 + (i & 31); }

// ---------------------------------------------------------------------------
// crf256: grid 2*BB blocks x 256 threads (4 waves) - best measured config
// (R11: 276 us crf, 347.9 us total).
//   block [0,BB)    : Viterbi values for b (2 thr/to, R[64] raw slice),
//                     exact alpha rows -> ws.
//   block [BB,2*BB) : forward-alg (R[64] exp slice), log-free recurrence,
//                     rescale every 4 steps; fused gold score -> gb.
// Padded LDS sections (h*72 base, 36-float sections) = proven 0-conflict
// 2-address broadcast. One barrier per step.
// ---------------------------------------------------------------------------
__global__ __launch_bounds__(256, 1) void crf256(
    const float* __restrict__ feats, const float* __restrict__ trans,
    const int* __restrict__ tags,
    float* __restrict__ pscore, int* __restrict__ lasttag,
    float* __restrict__ alphaS, float* __restrict__ gb)
{
  const int bid = blockIdx.x;
  const bool isv = bid < BB;
  const int b = isv ? bid : bid - BB;
  const int tid = threadIdx.x;
  const int to = tid >> 1;             // 0..127
  const int h  = tid & 1;              // 64-from slice
  const int lane = tid & 63;
  const int wv = tid >> 6;             // 0..3

  __shared__ __align__(16) float BUF[2][144];  // AV (vit) / P (fwd), padded
  __shared__ __align__(16) float pwm[4];       // fwd per-wave P-max
  __shared__ float vitm[2]; __shared__ int viti[2];
  __shared__ float reds[2]; __shared__ float redg[4];

  // 64-from transition slice in registers: raw (vit) / exp (fwd)
  float R[64];
  {
    const float4* tr = (const float4*)(trans + (size_t)to * KK + h * 64);
#pragma unroll
    for (int c = 0; c < 16; ++c) {
      float4 v = tr[c];
      if (isv) { R[4*c+0]=v.x; R[4*c+1]=v.y; R[4*c+2]=v.z; R[4*c+3]=v.w; }
      else     { R[4*c+0]=__expf(v.x); R[4*c+1]=__expf(v.y);
                 R[4*c+2]=__expf(v.z); R[4*c+3]=__expf(v.w); }
    }
  }

  if (h == 0) BUF[0][paddr(to)] = isv ? ((to==START_TAG)?0.0f:NEGV)
                                      : ((to==START_TAG)?1.0f:0.0f);
  __syncthreads();

  const float* fb = feats + (size_t)b * TT * KK + to;
  float* aSb = alphaS + (size_t)b * TT * KK + to;

  float M = 0.0f;                 // fwd accumulated log-scale
  float fcur = fb[0];
  int cur = 0;

#pragma unroll 4
  for (int t = 0; t < TT; ++t) {
    const int tn = (t + 1 < TT) ? t + 1 : t;
    float fnext = fb[(size_t)tn * KK];
    const float* Bc = &BUF[cur][0];
    const int base = h * 72;

    if (isv) {
      float4 p = *(const float4*)&Bc[base];
      float m0 = fmaxf(p.x + R[0], p.y + R[1]);
      float m1 = fmaxf(p.z + R[2], p.w + R[3]);
#pragma unroll
      for (int c = 1; c < 16; ++c) {
        p = *(const float4*)&Bc[base + (c>>3)*36 + (c&7)*4];
        m0 = max3f(m0, p.x + R[4*c+0], p.y + R[4*c+1]);
        m1 = max3f(m1, p.z + R[4*c+2], p.w + R[4*c+3]);
      }
      float m = fmaxf(m0, m1);
      m = fmaxf(m, dppf<0xB1>(m, m));       // merge h pair
      if (h == 0) {
        float a = m + fcur;
        BUF[cur ^ 1][paddr(to)] = a;
        aSb[(size_t)t * KK] = a;
      }
    } else {
      float corr = 1.0f;
      if ((t & 3) == 0 && t) {              // consume previous phase-3 maxes
        float4 w = *(const float4*)&pwm[0];
        float pmax = fmaxf(fmaxf(w.x, w.y), fmaxf(w.z, w.w));
        M += __logf(pmax);
        corr = 1.0f / pmax;
      }
      float s0=0.f, s1=0.f, s2=0.f, s3=0.f;
#pragma unroll
      for (int c = 0; c < 16; ++c) {
        float4 p = *(const float4*)&Bc[base + (c>>3)*36 + (c&7)*4];
        s0 = fmaf(R[4*c+0], p.x, s0);
        s1 = fmaf(R[4*c+1], p.y, s1);
        s2 = fmaf(R[4*c+2], p.z, s2);
        s3 = fmaf(R[4*c+3], p.w, s3);
      }
      float s = (s0 + s1) + (s2 + s3);
      s = s + dppf<0xB1>(s, s);             // merge h pair -> full row sum
      float ef = __expf(fcur);
      if ((t & 3) == 0 && t) ef *= corr;
      float pv = s * ef;                    // P_new (scaled)
      if (h == 0) BUF[cur ^ 1][paddr(to)] = pv;
      if ((t & 3) == 3) {                   // publish wave max of P
        float wm = wave_max63(pv);
        if (lane == 63) pwm[wv] = wm;
      }
    }
    __syncthreads();
    cur ^= 1;
    fcur = fnext;
  }

  // ---- terminal ----
  if (isv) {
    if (tid < KK) {
      float term = BUF[cur][paddr(tid)] + trans[(size_t)STOP_TAG * KK + tid];
      float m = term; int i = tid;
#pragma unroll
      for (int off = 1; off < 64; off <<= 1) {
        float mo = __shfl_xor(m, off, 64);
        int   io = __shfl_xor(i, off, 64);
        if (mo > m || (mo == m && io < i)) { m = mo; i = io; }
      }
      if (lane == 0) { vitm[tid >> 6] = m; viti[tid >> 6] = i; }
    }
    __syncthreads();
    if (tid == 0) {
      float m = vitm[0]; int i = viti[0];
      if (vitm[1] > m || (vitm[1] == m && viti[1] < i)) { m = vitm[1]; i = viti[1]; }
      pscore[b] = m; lasttag[b] = i;
    }
  } else {
    if (tid < KK) {
      float e = BUF[cur][paddr(tid)] * __expf(trans[(size_t)STOP_TAG * KK + tid]);
#pragma unroll
      for (int off = 1; off < 64; off <<= 1) e += __shfl_xor(e, off, 64);
      if (lane == 0) reds[tid >> 6] = e;
    }
    // fused gold score: 2 time-steps per thread
    const int* tg = tags + (size_t)b * TT;
    const float* fg = feats + (size_t)b * TT * KK;
    float g = 0.0f;
#pragma unroll
    for (int k2 = 0; k2 < 2; ++k2) {
      int t = tid + k2 * 256;
      int ct = tg[t];
      int pv2 = (t == 0) ? START_TAG : tg[t - 1];
      g += trans[(size_t)ct * KK + pv2] + fg[(size_t)t * KK + ct];
      if (t == TT - 1) g += trans[(size_t)STOP_TAG * KK + ct];
    }
#pragma unroll
    for (int off = 1; off < 64; off <<= 1) g += __shfl_xor(g, off, 64);
    if (lane == 0) redg[wv] = g;
    __syncthreads();
    if (tid == 0) {
      float sg = redg[0] + redg[1] + redg[2] + redg[3];
      gb[b] = (M + __logf(reds[0] + reds[1])) - sg;
    }
  }
}

// ---------------------------------------------------------------------------
// backtrace_loss: blocks [0,BB) backtrace per b; block BB reduces loss.
// ---------------------------------------------------------------------------
__global__ __launch_bounds__(64) void backtrace_loss(
    const float* __restrict__ alphaS, const float* __restrict__ trans,
    const int* __restrict__ lasttag, const float* __restrict__ gb,
    float* __restrict__ pred, float* __restrict__ loss_out)
{
  const int lane = threadIdx.x;
  if (blockIdx.x == BB) {
    float v = gb[lane] + gb[lane + 64] + gb[lane + 128] + gb[lane + 192];
#pragma unroll
    for (int off = 1; off < 64; off <<= 1) v += __shfl_xor(v, off, 64);
    if (lane == 0) loss_out[0] = v / (float)(BB * TT);
    return;
  }
  const int b = blockIdx.x;
  __shared__ float tl[KK * KK];                 // 64 KB
  {
    const float4* src = (const float4*)trans;
    float4* dst = (float4*)tl;
#pragma unroll
    for (int i = 0; i < (KK * KK / 4) / 64; ++i) dst[lane + i * 64] = src[lane + i * 64];
  }
  int tag = lasttag[b];
  if (lane == 0) pred[(size_t)b * TT + (TT - 1)] = (float)tag;
  const float* arow = alphaS + (size_t)b * TT * KK;

  float p0[8], p1[8];
#pragma unroll
  for (int j = 0; j < 8; ++j) {
    int r = TT - 2 - j;
    p0[j] = arow[(size_t)r * KK + lane];
    p1[j] = arow[(size_t)r * KK + 64 + lane];
  }
  __syncthreads();

  for (int rb = TT - 2; rb >= 0; rb -= 8) {
#pragma unroll
    for (int j = 0; j < 8; ++j) {
      int r = rb - j;
      if (r >= 0) {
        float x0 = p0[j] + tl[tag * KK + lane];
        float x1 = p1[j] + tl[tag * KK + 64 + lane];
        float m = fmaxf(x0, x1);
        float M = wave_max63(m);
        M = __int_as_float(__builtin_amdgcn_readlane(__float_as_int(M), 63));
        unsigned long long b0 = __ballot(x0 == M);
        unsigned long long b1 = __ballot(x1 == M);
        tag = b0 ? (int)__builtin_ctzll(b0) : 64 + (int)__builtin_ctzll(b1);
        if (lane == 0) pred[(size_t)b * TT + r] = (float)tag;
        int rp = r - 8;
        if (rp >= 0) {
          p0[j] = arow[(size_t)rp * KK + lane];
          p1[j] = arow[(size_t)rp * KK + 64 + lane];
        }
      }
    }
  }
}

// ===========================================================================
// Fallback path (ws too small for 64MB alpha store): R2-proven kernels.
// ===========================================================================
__global__ __launch_bounds__(768) void crf_main_fb(
    const float* __restrict__ feats, const float* __restrict__ trans,
    float* __restrict__ logz, float* __restrict__ pscore,
    int* __restrict__ lasttag, uint8_t* __restrict__ bptr)
{
  const int b = blockIdx.x;
  const int tid = threadIdx.x;
  const bool is_fwd = tid < 256;
  const int lane = tid & 63;

  __shared__ __align__(16) float P[2][144];
  __shared__ __align__(16) float AV[2][144];
  __shared__ __align__(16) float redmF[2][4];
  __shared__ float reds[4];
  __shared__ float vitm[8];
  __shared__ int   viti[8];

  int myto, h;
  if (is_fwd) { myto = tid >> 1; h = tid & 1; }
  else { int q = tid - 256; myto = q >> 2; h = q & 3; }

  float R[64];
  if (is_fwd) {
    const float4* tr = (const float4*)(trans + (size_t)myto * KK + h * 64);
#pragma unroll
    for (int c = 0; c < 16; ++c) {
      float4 v = tr[c];
      R[4*c+0]=expf(v.x); R[4*c+1]=expf(v.y); R[4*c+2]=expf(v.z); R[4*c+3]=expf(v.w);
    }
  } else {
    const float4* tr = (const float4*)(trans + (size_t)myto * KK + h * 32);
#pragma unroll
    for (int c = 0; c < 8; ++c) {
      float4 v = tr[c];
      R[4*c+0]=v.x; R[4*c+1]=v.y; R[4*c+2]=v.z; R[4*c+3]=v.w;
    }
  }

  if (is_fwd) { if (h == 0) P[0][paddr(myto)] = (myto==START_TAG)?1.0f:0.0f; }
  else        { if (h == 0) AV[0][paddr(myto)] = (myto==START_TAG)?0.0f:NEGV; }
  if (tid < 4) redmF[1][tid] = 0.0f;
  __syncthreads();

  const float* fb = feats + (size_t)b * TT * KK + myto;
  uint8_t* bp = bptr + (size_t)b * TT * KK + myto;

  float fcur = fb[0];
  float Mprev = 0.0f;
  float aCarry = 0.0f;
  int cur = 0;

  for (int t = 0; t < TT; ++t) {
    const int tn = (t + 1 < TT) ? t + 1 : t;
    float fnext = fb[(size_t)tn * KK];
    const int rd = (t + 1) & 1, wr = t & 1;

    if (is_fwd) {
      float4 rv = *(const float4*)&redmF[rd][0];
      float M1 = fmaxf(fmaxf(rv.x, rv.y), fmaxf(rv.z, rv.w));
      const float* Pc = &P[cur][0];
      const int base = h * 72;
      float s0=0.f, s1=0.f, s2=0.f, s3=0.f;
#pragma unroll
      for (int c = 0; c < 16; ++c) {
        float4 p = *(const float4*)&Pc[base + (c>>3)*36 + (c&7)*4];
        s0 = fmaf(R[4*c+0], p.x, s0);
        s1 = fmaf(R[4*c+1], p.y, s1);
        s2 = fmaf(R[4*c+2], p.z, s2);
        s3 = fmaf(R[4*c+3], p.w, s3);
      }
      float s = (s0 + s1) + (s2 + s3);
      s = s + dppf<0xB1>(s, s);
      float a = Mprev + logf(s) + fcur;
      float wm = wave_max63(a);
      if (lane == 63) redmF[wr][tid >> 6] = wm;
      float pv = expf(a - M1);
      if (h == 0) P[cur ^ 1][paddr(myto)] = pv;
      Mprev = M1;
      aCarry = a;
    } else {
      const float* Ac = &AV[cur][0];
      const int base = h * 36;
      const int fb0 = h * 32;
      float4 p0 = *(const float4*)&Ac[base];
      float m0 = p0.x + R[0], m1 = p0.y + R[1], m2 = p0.z + R[2], m3 = p0.w + R[3];
      int i0 = fb0, i1 = fb0+1, i2 = fb0+2, i3 = fb0+3;
#pragma unroll
      for (int c = 1; c < 8; ++c) {
        float4 p = *(const float4*)&Ac[base + c*4];
        float v0 = p.x + R[4*c+0]; if (v0 > m0) { m0 = v0; i0 = fb0+4*c+0; }
        float v1 = p.y + R[4*c+1]; if (v1 > m1) { m1 = v1; i1 = fb0+4*c+1; }
        float v2 = p.z + R[4*c+2]; if (v2 > m2) { m2 = v2; i2 = fb0+4*c+2; }
        float v3 = p.w + R[4*c+3]; if (v3 > m3) { m3 = v3; i3 = fb0+4*c+3; }
      }
      float m = m0; int i = i0;
      if (m1 > m || (m1 == m && i1 < i)) { m = m1; i = i1; }
      if (m2 > m || (m2 == m && i2 < i)) { m = m2; i = i2; }
      if (m3 > m || (m3 == m && i3 < i)) { m = m3; i = i3; }
      { float mo = dppf<0xB1>(m, m); int io = dppi<0xB1>(i, i);
        if (mo > m || (mo == m && io < i)) { m = mo; i = io; } }
      { float mo = dppf<0x4E>(m, m); int io = dppi<0x4E>(i, i);
        if (mo > m || (mo == m && io < i)) { m = mo; i = io; } }
      float a = m + fcur;
      if (h == 0) { AV[cur ^ 1][paddr(myto)] = a; bp[(size_t)t * KK] = (uint8_t)i; }
      aCarry = a;
    }
    __syncthreads();
    cur ^= 1;
    fcur = fnext;
  }

  float tstop = trans[(size_t)STOP_TAG * KK + myto];
  float term = aCarry + tstop;
  float M = 0.0f;
  if (is_fwd) {
    float wm = wave_max63(term);
    if (lane == 63) redmF[0][tid >> 6] = wm;
  } else {
    float m = term; int i = myto;
#pragma unroll
    for (int off = 1; off < 64; off <<= 1) {
      float mo = __shfl_xor(m, off, 64);
      int   io = __shfl_xor(i, off, 64);
      if (mo > m || (mo == m && io < i)) { m = mo; i = io; }
    }
    if (lane == 0) { vitm[(tid>>6)-4] = m; viti[(tid>>6)-4] = i; }
  }
  __syncthreads();
  if (is_fwd) {
    float4 rv = *(const float4*)&redmF[0][0];
    M = fmaxf(fmaxf(rv.x, rv.y), fmaxf(rv.z, rv.w));
    float e = (h == 0) ? expf(term - M) : 0.0f;
#pragma unroll
    for (int off = 1; off < 64; off <<= 1) e += __shfl_xor(e, off, 64);
    if (lane == 0) reds[tid >> 6] = e;
  } else if (tid == 256) {
    float m = vitm[0]; int i = viti[0];
#pragma unroll
    for (int w = 1; w < 8; ++w)
      if (vitm[w] > m || (vitm[w] == m && viti[w] < i)) { m = vitm[w]; i = viti[w]; }
    pscore[b] = m; lasttag[b] = i;
  }
  __syncthreads();
  if (tid == 0) logz[b] = M + logf(reds[0] + reds[1] + reds[2] + reds[3]);
}

__global__ __launch_bounds__(256) void backtrace_kernel(
    const uint8_t* __restrict__ bptr, const int* __restrict__ lasttag,
    float* __restrict__ pred)
{
  const int b = blockIdx.x;
  const int tid = threadIdx.x;
  __shared__ __align__(16) uint8_t lb[(TT / 2) * KK];
  __shared__ int tagcarry;
  if (tid == 0) tagcarry = lasttag[b];

  for (int half = 1; half >= 0; --half) {
    __syncthreads();
    const float4* src = reinterpret_cast<const float4*>(
        bptr + ((size_t)b * TT + (size_t)half * (TT / 2)) * KK);
    float4* dst = reinterpret_cast<float4*>(lb);
    for (int i = tid; i < (TT / 2) * KK / 16; i += 256) dst[i] = src[i];
    __syncthreads();
    if (tid == 0) {
      int tag = tagcarry;
      for (int t = TT / 2 - 1; t >= 0; --t) {
        int gt = half * (TT / 2) + t;
        pred[(size_t)b * TT + gt] = (float)tag;
        tag = lb[t * KK + tag];
      }
      tagcarry = tag;
    }
  }
}

__global__ __launch_bounds__(64) void gold_kernel(
    const float* __restrict__ feats, const int* __restrict__ tags,
    const float* __restrict__ trans, const float* __restrict__ logz,
    float* __restrict__ gb)
{
  const int b = blockIdx.x;
  const int lane = threadIdx.x;
  const int* tg = tags + (size_t)b * TT;
  const float* fb = feats + (size_t)b * TT * KK;
  float g = 0.0f;
#pragma unroll
  for (int k = 0; k < TT / 64; ++k) {
    int t = lane * (TT / 64) + k;
    int ct = tg[t];
    int pv = (t == 0) ? START_TAG : tg[t - 1];
    g += trans[ct * KK + pv] + fb[(size_t)t * KK + ct];
  }
  if (lane == 63) g += trans[STOP_TAG * KK + tg[TT - 1]];
#pragma unroll
  for (int off = 1; off <= 32; off <<= 1) g += __shfl_xor(g, off, 64);
  if (lane == 0) gb[b] = logz[b] - g;
}

__global__ __launch_bounds__(256) void loss_reduce(
    const float* __restrict__ gb, float* __restrict__ out)
{
  const int tid = threadIdx.x;
  const int lane = tid & 63, wv = tid >> 6;
  float v = gb[tid];
#pragma unroll
  for (int off = 1; off <= 32; off <<= 1) v += __shfl_xor(v, off, 64);
  __shared__ float red[4];
  if (lane == 0) red[wv] = v;
  __syncthreads();
  if (tid == 0) out[0] = (red[0] + red[1] + red[2] + red[3]) / (float)(BB * TT);
}

// ---------------------------------------------------------------------------
extern "C" void kernel_launch(void* const* d_in, const int* in_sizes, int n_in,
                              void* d_out, int out_size, void* d_ws, size_t ws_size,
                              hipStream_t stream) {
  const float* feats = (const float*)d_in[0];
  const int*   tags  = (const int*)d_in[1];
  const float* trans = (const float*)d_in[2];

  float* out    = (float*)d_out;
  float* loss   = out;
  float* pscore = out + 1;
  float* pred   = out + 1 + BB;
  (void)in_sizes; (void)n_in; (void)out_size;

  const size_t alpha_bytes = (size_t)BB * TT * KK * sizeof(float);   // 64 MB
  const bool cheap = ws_size >= alpha_bytes + 4096;

  if (cheap) {
    float* alphaS  = (float*)d_ws;
    char*  wsend   = (char*)d_ws + alpha_bytes;
    int*   lasttag = (int*)(wsend);
    float* gb      = (float*)(wsend + BB * sizeof(int));
    crf256<<<2 * BB, 256, 0, stream>>>(feats, trans, tags, pscore, lasttag,
                                       alphaS, gb);
    backtrace_loss<<<BB + 1, 64, 0, stream>>>(alphaS, trans, lasttag, gb,
                                              pred, loss);
  } else {
    uint8_t* bptr    = (uint8_t*)d_ws;
    char*    wsend   = (char*)d_ws + (size_t)BB * TT * KK;
    float*   logz    = (float*)(wsend);
    int*     lasttag = (int*)(wsend + BB * sizeof(float));
    float*   gb      = (float*)(wsend + BB * sizeof(float) + BB * sizeof(int));
    crf_main_fb<<<BB, 768, 0, stream>>>(feats, trans, logz, pscore, lasttag, bptr);
    backtrace_kernel<<<BB, 256, 0, stream>>>(bptr, lasttag, pred);
    gold_kernel<<<BB, 64, 0, stream>>>(feats, tags, trans, logz, gb);
    loss_reduce<<<1, 256, 0, stream>>>(gb, loss);
  }
}